// Round 15
// baseline (523.876 us; speedup 1.0000x reference)
//
#include <hip/hip_runtime.h>

// GAT_30039001268364: 3-layer GAT + BN + residual + mean-pool + MLP on MI355X.
// Runtime-adaptive input dtypes (f32-vs-bf16, int64-vs-int32, per-wave ballot probe).
// R15: k_gemm goes LDS-free — B-fragments read directly from the 32KB L1-resident
// weight table (kills wt staging + __syncthreads barrier; MFMA/load interleave
// with waves retiring independently). gemm01 unchanged.

#define NN   50000
#define NE   800000
#define NET  (NE + NN)
#define HD   128
#define NG   64
#define NB   196          // ceil(NN/256)
#define NBN  391          // ceil(NN/128)  — BN stats blocks
#define NGB  782          // ceil(NN/64)   — GEMM blocks
#define NCH  20           // pool chunks per graph
#define NTILE 3321        // ceil(NET/256) — edge tiles
#define PSZ  6250         // dst-partition size (8 partitions)

typedef unsigned short u16;
typedef __attribute__((ext_vector_type(8))) short short8;
typedef __attribute__((ext_vector_type(4))) float f32x4;

// ---- canonical parameter pool offsets (bf16 elements) ----
#define O_WEMB 0
#define O_BEMB 16384
#define O_CW   16512
#define O_CAS  49280
#define O_CAD  49536
#define O_CB   49792
#define O_C2W  50048
#define O_C2AS 66432
#define O_C2AD 66560
#define O_C2B  66688
#define O_BNG  66816
#define O_BNB  67200
#define O_L1W  67584
#define O_L1B  83968
#define O_L2W  84096
#define O_L2B  100480
#define O_L3W  100608
#define O_L3B  101888
#define NPAR   101898

// ---- persistent device scratch ----
__device__ int   g_f32flag;
__device__ __align__(16) u16 g_x [NN*HD];
__device__ __align__(16) u16 g_par[NPAR];
__device__ int   g_src[NE], g_dst[NE], g_batch[NN];
__device__ __align__(16) u16 g_hb[NN*HD];   // residual stream h, bf16
__device__ __align__(16) u16 g_hw[NN*HD];
__device__ __align__(16) u16 g_c[NN*HD];    // conv output, bf16
__device__ float g_asrc[NN*8];
__device__ float g_adst[NN*8];
__device__ int   g_rowptr[NN+1];
__device__ int   g_cursor[NN];
__device__ int   g_bsum[NB], g_boff[NB];
__device__ int   g_csr[NET];
__device__ float g_bnp1[NBN*HD], g_bnp2[NBN*HD];
__device__ __align__(16) float g_scl[HD];
__device__ __align__(16) float g_shf[HD];
__device__ int   g_gcnt[NG], g_goff[NG];
__device__ __align__(16) float g_poolp[NG*NCH*HD];
__device__ __align__(16) u16 g_WT[4][HD*HD];

__device__ __forceinline__ float b2f(u16 u) {
    unsigned v = ((unsigned)u) << 16; float f; __builtin_memcpy(&f, &v, 4); return f;
}
__device__ __forceinline__ u16 f2b(float f) {
    unsigned v; __builtin_memcpy(&v, &f, 4);
    return (u16)((v + 0x7fffu + ((v >> 16) & 1u)) >> 16);   // RNE
}

// wave-uniform dtype probes (64 fixed samples, ballot — deterministic)
__device__ __forceinline__ int probe_f32(const void* xp) {
    const u16* p = (const u16*)xp;
    int ex = (p[threadIdx.x & 63] >> 7) & 0xff;
    return __ballot(ex >= 0x93) != 0ULL;   // |v|>=2^20: impossible for bf16 acts
}
__device__ __forceinline__ int probe_i64(const void* eip) {
    const int* q = (const int*)eip;
    return __ballot(q[2*(threadIdx.x & 63) + 1] != 0) == 0ULL; // i64: high words 0
}

// intra-block inclusive scan (256 threads = 4 waves), shuffle-based
__device__ __forceinline__ int block_incl_scan(int v, int* lds4) {
    int t = threadIdx.x, lane = t & 63, w = t >> 6;
    #pragma unroll
    for (int d = 1; d < 64; d <<= 1) {
        int o = __shfl_up(v, d);
        if (lane >= d) v += o;
    }
    if (lane == 63) lds4[w] = v;
    __syncthreads();
    if (w == 0 && lane < 4) {
        int s = lds4[lane];
        #pragma unroll
        for (int d = 1; d < 4; d <<= 1) {
            int o = __shfl_up(s, d);
            if (lane >= d) s += o;
        }
        lds4[lane] = s;
    }
    __syncthreads();
    if (w > 0) v += lds4[w-1];
    return v;
}

// ---- canonicalize x + params (+ cursor init + flag publish) ----
struct P18 { const void* p[18]; int off[18]; int n[18]; };
__global__ void k_convx(const void* xp, P18 a) {    // grid 6250 x 256
    int gi = blockIdx.x*256 + threadIdx.x;
    int f32 = probe_f32(xp);
    if (gi == 0) g_f32flag = f32;
    if (gi < NN) g_cursor[gi] = 1;           // self-loop pre-count
    int i = gi*4;
    if (f32) {
        float4 v = *(const float4*)((const float*)xp + i);
        ushort4 o = { f2b(v.x), f2b(v.y), f2b(v.z), f2b(v.w) };
        *(ushort4*)&g_x[i] = o;
    } else {
        *(ushort4*)&g_x[i] = *(const ushort4*)((const u16*)xp + i);
    }
    if (blockIdx.x < 64) {                   // folded param conversion
        for (int t = 0; t < 18; ++t) {
            const void* s = a.p[t]; int off = a.off[t], n = a.n[t];
            for (int j = blockIdx.x*256 + threadIdx.x; j < n; j += 64*256)
                g_par[off+j] = f32 ? f2b(((const float*)s)[j]) : ((const u16*)s)[j];
        }
    }
}

// ---- edge/batch conversion + degree count + folded weight transposes ----
__global__ void k_convidx(const void* ei, const void* ba) {   // grid 3125+256
    int b = blockIdx.x;
    if (b >= 3125) {                         // transpose blocks (g_par from k_convx)
        int bb = b - 3125;
        int which = bb >> 6;
        int poff = which==0 ? O_WEMB : which==1 ? O_CW : which==2 ? (O_CW+16384) : O_C2W;
        int idx = (bb & 63)*256 + threadIdx.x;
        int n = idx >> 7, k = idx & 127;
        g_WT[which][n*HD + k] = g_par[poff + k*HD + n];
        return;
    }
    int i64 = probe_i64(ei);
    int e = b*256 + threadIdx.x;
    if (e < NE) {
        int s, d;
        if (i64) { s = (int)((const long long*)ei)[e]; d = (int)((const long long*)ei)[NE + e]; }
        else     { s = ((const int*)ei)[e];            d = ((const int*)ei)[NE + e]; }
        g_src[e] = s; g_dst[e] = d;
        atomicAdd(&g_cursor[d], 1);
    }
    if (e < NN)
        g_batch[e] = i64 ? (int)((const long long*)ba)[e] : ((const int*)ba)[e];
}

// ---- hierarchical exclusive scan of degree counts ----
__global__ void k_blocksum() {
    int i = blockIdx.x*256 + threadIdx.x;
    int v = (i < NN) ? g_cursor[i] : 0;
    #pragma unroll
    for (int d = 32; d; d >>= 1) v += __shfl_down(v, d);
    __shared__ int lds[4];
    if ((threadIdx.x & 63) == 0) lds[threadIdx.x >> 6] = v;
    __syncthreads();
    if (threadIdx.x == 0) g_bsum[blockIdx.x] = lds[0]+lds[1]+lds[2]+lds[3];
}
// ---- small ops: block-sum scan (block 0), graph-offset search (block 1) ----
__global__ void k_misc() {
    int b = blockIdx.x, t = threadIdx.x;
    if (b == 0) {
        __shared__ int lds[4];
        int v = (t < NB) ? g_bsum[t] : 0;
        int incl = block_incl_scan(v, lds);
        if (t < NB) g_boff[t] = incl - v;     // exclusive
    } else {
        __shared__ int off[NG+1];
        if (t <= NG) {
            int lo = 0, hi = NN;
            while (lo < hi) { int mid = (lo+hi) >> 1; if (g_batch[mid] < t) lo = mid+1; else hi = mid; }
            off[t] = lo;
        }
        __syncthreads();
        if (t < NG) { g_goff[t] = off[t]; g_gcnt[t] = off[t+1] - off[t]; }
    }
}
__global__ void k_downsweep() {
    __shared__ int lds[4];
    int i = blockIdx.x*256 + threadIdx.x;
    int c = (i < NN) ? g_cursor[i] : 0;
    int incl = block_incl_scan(c, lds);
    int base = g_boff[blockIdx.x];
    if (i < NN) {
        g_rowptr[i+1] = base + incl;
        g_cursor[i]   = base + incl - c;  // exclusive start = scatter cursor
    }
    if (i == 0) g_rowptr[0] = 0;
}

// ---- scatter, XCD-affine dst partitioning; src loaded only post-check ----
__global__ void k_scatter() {   // grid NTILE*8
    int part = blockIdx.x & 7;
    int e = (blockIdx.x >> 3)*256 + threadIdx.x;
    if (e >= NET) return;
    int d = (e < NE) ? g_dst[e] : e - NE;
    if (d / PSZ != part) return;
    int s = (e < NE) ? g_src[e] : d;
    int pos = atomicAdd(&g_cursor[d], 1);
    g_csr[pos] = s;
}

// ---- shared epilogue helper: att-logit shuffle reduction ----
__device__ __forceinline__ void att_epilogue(f32x4* acc, int row0, int nrows,
                                             int asoff, int adoff, int heads,
                                             int m16, int q) {
    #pragma unroll
    for (int reg = 0; reg < 4; ++reg) {
        float v[8], u[8];
        #pragma unroll
        for (int ct = 0; ct < 8; ++ct) {
            float w = acc[ct][reg];
            v[ct] = w * b2f(g_par[asoff + ct*16 + m16]);
            u[ct] = w * b2f(g_par[adoff + ct*16 + m16]);
        }
        #pragma unroll
        for (int d = 1; d < 16; d <<= 1)
            #pragma unroll
            for (int ct = 0; ct < 8; ++ct) {
                v[ct] += __shfl_xor(v[ct], d);
                u[ct] += __shfl_xor(u[ct], d);
            }
        int r = row0 + q*4 + reg;
        if (m16 == 0 && r < nrows) {
            if (heads == 8) {
                #pragma unroll
                for (int h = 0; h < 8; ++h) {
                    g_asrc[r*8 + h] = v[h];
                    g_adst[r*8 + h] = u[h];
                }
            } else {
                float sv = 0.f, su = 0.f;
                #pragma unroll
                for (int ct = 0; ct < 8; ++ct) { sv += v[ct]; su += u[ct]; }
                g_asrc[r] = sv; g_adst[r] = su;
            }
        }
    }
}

// ---- fused embedding GEMM + layer-0 conv GEMM ----
__global__ __launch_bounds__(256) void k_gemm01() {
    __shared__ __align__(16) u16 wt[HD*136];
    __shared__ __align__(16) u16 ldh[64*136];
    int t = threadIdx.x;
    int lane = t & 63, wave = t >> 6;
    int m16 = lane & 15, q = lane >> 4;
    int row0 = blockIdx.x*64 + wave*16;
    // ---- phase 1: h = x @ W_emb + b_emb ----
    #pragma unroll
    for (int i = 0; i < 8; ++i) {
        int e = (t + i*256) * 8;
        int n = e >> 7, k = e & 127;
        *(uint4*)&wt[n*136 + k] = *(const uint4*)&g_WT[0][e];
    }
    __syncthreads();
    int ra = row0 + m16; if (ra > NN-1) ra = NN-1;
    int rbase = ra*HD + q*8;
    short8 af[4];
    #pragma unroll
    for (int kc = 0; kc < 4; ++kc) af[kc] = *(const short8*)&g_x[rbase + kc*32];
    f32x4 acc[8];
    #pragma unroll
    for (int b = 0; b < 8; ++b) acc[b] = (f32x4){0.f,0.f,0.f,0.f};
    #pragma unroll
    for (int kc = 0; kc < 4; ++kc)
        #pragma unroll
        for (int ct = 0; ct < 8; ++ct) {
            short8 bf = *(const short8*)&wt[(ct*16 + m16)*136 + kc*32 + q*8];
            acc[ct] = __builtin_amdgcn_mfma_f32_16x16x32_bf16(af[kc], bf, acc[ct], 0,0,0);
        }
    #pragma unroll
    for (int reg = 0; reg < 4; ++reg) {
        int rl = wave*16 + q*4 + reg;
        #pragma unroll
        for (int ct = 0; ct < 8; ++ct) {
            int c = ct*16 + m16;
            ldh[rl*136 + c] = f2b(acc[ct][reg] + b2f(g_par[O_BEMB + c]));
        }
    }
    __syncthreads();
    {
        int rl = t >> 2, ck = (t & 3)*32;
        int r = blockIdx.x*64 + rl;
        if (r < NN) {
            uint4 d0 = *(uint4*)&ldh[rl*136 + ck];
            uint4 d1 = *(uint4*)&ldh[rl*136 + ck + 8];
            uint4 d2 = *(uint4*)&ldh[rl*136 + ck + 16];
            uint4 d3 = *(uint4*)&ldh[rl*136 + ck + 24];
            u16* dst = g_hb + r*HD + ck;
            *(uint4*)&dst[0]  = d0; *(uint4*)&dst[8]  = d1;
            *(uint4*)&dst[16] = d2; *(uint4*)&dst[24] = d3;
        }
    }
    // ---- phase 2: hw = h @ W0, att logits (heads=8) ----
    #pragma unroll
    for (int i = 0; i < 8; ++i) {
        int e = (t + i*256) * 8;
        int n = e >> 7, k = e & 127;
        *(uint4*)&wt[n*136 + k] = *(const uint4*)&g_WT[1][e];
    }
    __syncthreads();
    int rl2 = wave*16 + m16;
    #pragma unroll
    for (int kc = 0; kc < 4; ++kc) af[kc] = *(const short8*)&ldh[rl2*136 + kc*32 + q*8];
    #pragma unroll
    for (int b = 0; b < 8; ++b) acc[b] = (f32x4){0.f,0.f,0.f,0.f};
    #pragma unroll
    for (int kc = 0; kc < 4; ++kc)
        #pragma unroll
        for (int ct = 0; ct < 8; ++ct) {
            short8 bf = *(const short8*)&wt[(ct*16 + m16)*136 + kc*32 + q*8];
            acc[ct] = __builtin_amdgcn_mfma_f32_16x16x32_bf16(af[kc], bf, acc[ct], 0,0,0);
        }
    #pragma unroll
    for (int reg = 0; reg < 4; ++reg) {
        int r = row0 + q*4 + reg;
        if (r < NN) {
            #pragma unroll
            for (int ct = 0; ct < 8; ++ct)
                g_hw[r*HD + ct*16 + m16] = f2b(acc[ct][reg]);
        }
    }
    att_epilogue(acc, row0, NN, O_CAS, O_CAD, 8, m16, q);
}

// ---- conv GEMM, LDS-free (R15): B-frags straight from 32KB L1-resident g_WT;
// no staging, no barrier — MFMA/global-load interleave, waves retire freely.
// BN(L-1)+ReLU+residual fused prologue; att-logit epilogue.
__global__ __launch_bounds__(256) void k_gemm(int wsel, int nrows,
                                              int asoff, int adoff, int heads) {
    const u16* WTg = g_WT[wsel];
    int t = threadIdx.x;
    int lane = t & 63;
    int m16 = lane & 15, q = lane >> 4;
    int row0 = blockIdx.x*64 + (t >> 6)*16;
    int ra = row0 + m16; if (ra > nrows-1) ra = nrows-1;
    int rbase = ra*HD + q*8;
    // BN scale/shift for this lane's 8-channel slices (f32 tables, L2-hot)
    float4 sc[4][2], sf[4][2];
    #pragma unroll
    for (int kc = 0; kc < 4; ++kc) {
        sc[kc][0] = *(const float4*)&g_scl[kc*32 + q*8];
        sc[kc][1] = *(const float4*)&g_scl[kc*32 + q*8 + 4];
        sf[kc][0] = *(const float4*)&g_shf[kc*32 + q*8];
        sf[kc][1] = *(const float4*)&g_shf[kc*32 + q*8 + 4];
    }
    short8 cv[4], hv[4], af[4];
    #pragma unroll
    for (int kc = 0; kc < 4; ++kc) cv[kc] = *(const short8*)&g_c[rbase + kc*32];
    #pragma unroll
    for (int kc = 0; kc < 4; ++kc) hv[kc] = *(const short8*)&g_hb[rbase + kc*32];
    #pragma unroll
    for (int kc = 0; kc < 4; ++kc) {
        #pragma unroll
        for (int k2 = 0; k2 < 8; ++k2) {
            float scl = (k2 < 4) ? (&sc[kc][0].x)[k2] : (&sc[kc][1].x)[k2-4];
            float shf = (k2 < 4) ? (&sf[kc][0].x)[k2] : (&sf[kc][1].x)[k2-4];
            float v = fmaxf(b2f((u16)cv[kc][k2])*scl + shf, 0.f) + b2f((u16)hv[kc][k2]);
            af[kc][k2] = (short)f2b(v);
        }
        *(short8*)&g_hb[rbase + kc*32] = af[kc];   // unique per element; dup rows identical
    }
    f32x4 acc[8];
    #pragma unroll
    for (int b = 0; b < 8; ++b) acc[b] = (f32x4){0.f,0.f,0.f,0.f};
    #pragma unroll
    for (int kc = 0; kc < 4; ++kc)
        #pragma unroll
        for (int ct = 0; ct < 8; ++ct) {
            short8 bf = *(const short8*)&WTg[(ct*16 + m16)*HD + kc*32 + q*8];
            acc[ct] = __builtin_amdgcn_mfma_f32_16x16x32_bf16(af[kc], bf, acc[ct], 0,0,0);
        }
    #pragma unroll
    for (int reg = 0; reg < 4; ++reg) {
        int r = row0 + q*4 + reg;
        if (r < nrows) {
            #pragma unroll
            for (int ct = 0; ct < 8; ++ct)
                g_hw[r*HD + ct*16 + m16] = f2b(acc[ct][reg]);
        }
    }
    att_epilogue(acc, row0, nrows, asoff, adoff, heads, m16, q);
}

// ---- segment softmax + aggregate: one wave per dst node, 8/4/1 edge batching ----
__global__ __launch_bounds__(256) void k_flash(int boff, int heads, int hs) {
    int node = blockIdx.x*4 + (threadIdx.x >> 6);
    int lane = threadIdx.x & 63;
    int c0 = lane*2;
    int head = c0 >> hs;
    float ad = g_adst[node*heads + head];
    int beg = g_rowptr[node], end = g_rowptr[node+1];
    float l = 0.f, o0 = 0.f, o1 = 0.f;
    int j = beg;
    for (; j + 8 <= end; j += 8) {
        int s[8]; float av[8]; unsigned w[8];
        #pragma unroll
        for (int k = 0; k < 8; ++k) s[k] = g_csr[j+k];
        #pragma unroll
        for (int k = 0; k < 8; ++k) av[k] = g_asrc[s[k]*heads + head];
        #pragma unroll
        for (int k = 0; k < 8; ++k) w[k] = *(const unsigned*)&g_hw[s[k]*HD + c0];
        #pragma unroll
        for (int k = 0; k < 8; ++k) {
            float e = av[k] + ad;
            e = fmaxf(e, 0.2f*e);
            float p = __expf(fminf(e, 30.f));
            l  += p;
            o0 += p*b2f((u16)(w[k] & 0xffff));
            o1 += p*b2f((u16)(w[k] >> 16));
        }
    }
    for (; j + 4 <= end; j += 4) {
        int s[4]; float av[4]; unsigned w[4];
        #pragma unroll
        for (int k = 0; k < 4; ++k) s[k] = g_csr[j+k];
        #pragma unroll
        for (int k = 0; k < 4; ++k) av[k] = g_asrc[s[k]*heads + head];
        #pragma unroll
        for (int k = 0; k < 4; ++k) w[k] = *(const unsigned*)&g_hw[s[k]*HD + c0];
        #pragma unroll
        for (int k = 0; k < 4; ++k) {
            float e = av[k] + ad;
            e = fmaxf(e, 0.2f*e);
            float p = __expf(fminf(e, 30.f));
            l  += p;
            o0 += p*b2f((u16)(w[k] & 0xffff));
            o1 += p*b2f((u16)(w[k] >> 16));
        }
    }
    for (; j < end; ++j) {
        int s = g_csr[j];
        float e = g_asrc[s*heads + head] + ad;
        e = fmaxf(e, 0.2f*e);
        float p = __expf(fminf(e, 30.f));
        unsigned w = *(const unsigned*)&g_hw[s*HD + c0];
        l  += p;
        o0 += p*b2f((u16)(w & 0xffff));
        o1 += p*b2f((u16)(w >> 16));
    }
    float inv = 1.f/l;                       // l>0: self-loop guarantees >=1 edge
    ushort2 o = { f2b(o0*inv + b2f(g_par[boff + c0])),
                  f2b(o1*inv + b2f(g_par[boff + c0 + 1])) };
    *(ushort2*)&g_c[node*HD + c0] = o;       // bf16 store
}

// ---- BatchNorm: per-block partials + parallel reduce (kernel boundary is the
// ---- cheap cross-XCD fence; R11's fence-fused version lost 100us) ----
__global__ void k_bnstats() {
    int t = threadIdx.x; int ch = t & 127, r0 = t >> 7;
    int base = blockIdx.x*128;
    float s = 0.f, q = 0.f;
    for (int i = r0; i < 128; i += 2) {
        int n = base + i;
        if (n < NN) { float v = b2f(g_c[n*HD + ch]); s += v; q += v*v; }
    }
    __shared__ float sS[256], sQ[256];
    sS[t] = s; sQ[t] = q; __syncthreads();
    if (t < 128) {
        g_bnp1[blockIdx.x*HD + t] = sS[t] + sS[t+128];
        g_bnp2[blockIdx.x*HD + t] = sQ[t] + sQ[t+128];
    }
}
__global__ void k_bnfinal(int goff, int boff) {   // 128 blocks x 64
    int ch = blockIdx.x, t = threadIdx.x;
    float s = 0.f, q = 0.f;
    for (int b = t; b < NBN; b += 64) { s += g_bnp1[b*HD + ch]; q += g_bnp2[b*HD + ch]; }
    #pragma unroll
    for (int d = 32; d; d >>= 1) { s += __shfl_down(s, d); q += __shfl_down(q, d); }
    if (t == 0) {
        float mean = s / (float)NN;
        float var  = fmaxf(q / (float)NN - mean*mean, 0.f);
        float sc = b2f(g_par[goff + ch]) * rsqrtf(var + 1e-5f);
        g_scl[ch] = sc;
        g_shf[ch] = b2f(g_par[boff + ch]) - mean*sc;
    }
}

// ---- mean pool, stage 1 + fused layer-2 BN/ReLU/residual (bf16 streams) ----
__global__ void k_pool() {
    int g = blockIdx.x / NCH, c = blockIdx.x - g*NCH;
    int cnt = g_gcnt[g], off = g_goff[g];
    int step = (cnt + NCH - 1) / NCH;
    int r0 = c*step, r1 = min(cnt, r0 + step);
    int t = threadIdx.x;
    int ch = (t & 31) * 4;
    int rr = t >> 5;
    float sc0 = g_scl[ch], sc1 = g_scl[ch+1], sc2 = g_scl[ch+2], sc3 = g_scl[ch+3];
    float sf0 = g_shf[ch], sf1 = g_shf[ch+1], sf2 = g_shf[ch+2], sf3 = g_shf[ch+3];
    float4 s = {0.f,0.f,0.f,0.f};
    for (int i = r0 + rr; i < r1; i += 8) {
        int base = (off + i)*HD + ch;
        ushort4 cv = *(const ushort4*)&g_c[base];
        ushort4 hv = *(const ushort4*)&g_hb[base];
        s.x += fmaxf(b2f(cv.x)*sc0 + sf0, 0.f) + b2f(hv.x);
        s.y += fmaxf(b2f(cv.y)*sc1 + sf1, 0.f) + b2f(hv.y);
        s.z += fmaxf(b2f(cv.z)*sc2 + sf2, 0.f) + b2f(hv.z);
        s.w += fmaxf(b2f(cv.w)*sc3 + sf3, 0.f) + b2f(hv.w);
    }
    __shared__ float4 sh[256];
    sh[t] = s; __syncthreads();
    if (t < 32) {
        float4 a = sh[t];
        #pragma unroll
        for (int k = 1; k < 8; ++k) {
            float4 b = sh[t + k*32];
            a.x += b.x; a.y += b.y; a.z += b.z; a.w += b.w;
        }
        *(float4*)&g_poolp[(g*NCH + c)*HD + ch] = a;
    }
}

// ---- fused head: pool-reduce + lin1 + lin2 + lin3, one block per graph ----
__global__ void k_head(void* outB) {
    __shared__ float pl[HD], h1[HD], h2[HD];
    int g = blockIdx.x, t = threadIdx.x;   // 128 threads
    float s = 0.f;
    for (int c = 0; c < NCH; ++c) s += g_poolp[(g*NCH + c)*HD + t];
    pl[t] = s / fmaxf((float)g_gcnt[g], 1.f);
    __syncthreads();
    float acc = b2f(g_par[O_L1B + t]);
    for (int k = 0; k < HD; ++k) acc += pl[k] * b2f(g_par[O_L1W + k*HD + t]);
    h1[t] = fmaxf(acc, 0.f);
    __syncthreads();
    acc = b2f(g_par[O_L2B + t]);
    for (int k = 0; k < HD; ++k) acc += h1[k] * b2f(g_par[O_L2W + k*HD + t]);
    h2[t] = fmaxf(acc, 0.f);
    __syncthreads();
    if (t < 10) {
        acc = b2f(g_par[O_L3B + t]);
        for (int k = 0; k < HD; ++k) acc += h2[k] * b2f(g_par[O_L3W + k*10 + t]);
        if (g_f32flag) ((float*)outB)[g*10 + t] = acc;
        else           ((u16*)outB)[g*10 + t] = f2b(acc);
    }
}

extern "C" void kernel_launch(void* const* d_in, const int* in_sizes, int n_in,
                              void* d_out, int out_size, void* d_ws, size_t ws_size,
                              hipStream_t stream) {
    const void* x     = d_in[0];
    const void* ei    = d_in[1];
    const void* batch = d_in[3];

    P18 a;
    const int srcidx[18] = {4,5,6,7,8,9,10,11,12,13,14,15,16,17,18,19,20,21};
    const int offs[18] = {O_WEMB,O_BEMB,O_CW,O_CAS,O_CAD,O_CB,O_C2W,O_C2AS,O_C2AD,
                          O_C2B,O_BNG,O_BNB,O_L1W,O_L1B,O_L2W,O_L2B,O_L3W,O_L3B};
    const int lens[18] = {16384,128,32768,256,256,256,16384,128,128,128,384,384,
                          16384,128,16384,128,1280,10};
    for (int t = 0; t < 18; ++t) { a.p[t] = d_in[srcidx[t]]; a.off[t] = offs[t]; a.n[t] = lens[t]; }

    k_convx<<<6250, 256, 0, stream>>>(x, a);          // x + params + cursor + flag
    k_convidx<<<3125 + 256, 256, 0, stream>>>(ei, batch); // edges + batch + transposes
    k_blocksum<<<NB, 256, 0, stream>>>();
    k_misc<<<2, 256, 0, stream>>>();                  // scanb + gidx
    k_downsweep<<<NB, 256, 0, stream>>>();
    k_scatter<<<NTILE*8, 256, 0, stream>>>();         // XCD-affine partitions

    // fused: h = x@W_emb + b  AND  hw = h@W0 + att logits (layer 0)
    k_gemm01<<<NGB, 256, 0, stream>>>();
    k_flash<<<12500, 256, 0, stream>>>(O_CB, 8, 4);
    k_bnstats<<<NBN, 256, 0, stream>>>();
    k_bnfinal<<<128, 64, 0, stream>>>(O_BNG, O_BNB);

    for (int L = 1; L < 3; ++L) {
        int heads = (L < 2) ? 8 : 1;
        int hs    = (L < 2) ? 4 : 7;
        int as    = (L < 2) ? O_CAS + L*128 : O_C2AS;
        int ad    = (L < 2) ? O_CAD + L*128 : O_C2AD;
        int cb    = (L < 2) ? O_CB  + L*128 : O_C2B;
        k_gemm<<<NGB, 256, 0, stream>>>(L+1, NN, as, ad, heads);  // BN(L-1) fused prologue
        k_flash<<<12500, 256, 0, stream>>>(cb, heads, hs);
        k_bnstats<<<NBN, 256, 0, stream>>>();
        k_bnfinal<<<128, 64, 0, stream>>>(O_BNG + L*HD, O_BNB + L*HD);
    }

    k_pool<<<NG*NCH, 256, 0, stream>>>();             // + fused layer-2 BN/residual
    k_head<<<NG, 128, 0, stream>>>(d_out);
}

// Round 16
// 506.382 us; speedup vs baseline: 1.0345x; 1.0345x over previous
//
#include <hip/hip_runtime.h>

// GAT_30039001268364: 3-layer GAT + BN + residual + mean-pool + MLP on MI355X.
// Runtime-adaptive input dtypes (f32-vs-bf16, int64-vs-int32, per-wave ballot probe).
// R16: revert to R14's best-known config (514.7us). R15's LDS-free gemm was -9us
// (L1 thrash); 64-row LDS k_gemm is the verified floor among 3 structures tried.

#define NN   50000
#define NE   800000
#define NET  (NE + NN)
#define HD   128
#define NG   64
#define NB   196          // ceil(NN/256)
#define NBN  391          // ceil(NN/128)  — BN stats blocks
#define NGB  782          // ceil(NN/64)   — GEMM blocks
#define NCH  20           // pool chunks per graph
#define NTILE 3321        // ceil(NET/256) — edge tiles
#define PSZ  6250         // dst-partition size (8 partitions)

typedef unsigned short u16;
typedef __attribute__((ext_vector_type(8))) short short8;
typedef __attribute__((ext_vector_type(4))) float f32x4;

// ---- canonical parameter pool offsets (bf16 elements) ----
#define O_WEMB 0
#define O_BEMB 16384
#define O_CW   16512
#define O_CAS  49280
#define O_CAD  49536
#define O_CB   49792
#define O_C2W  50048
#define O_C2AS 66432
#define O_C2AD 66560
#define O_C2B  66688
#define O_BNG  66816
#define O_BNB  67200
#define O_L1W  67584
#define O_L1B  83968
#define O_L2W  84096
#define O_L2B  100480
#define O_L3W  100608
#define O_L3B  101888
#define NPAR   101898

// ---- persistent device scratch ----
__device__ int   g_f32flag;
__device__ __align__(16) u16 g_x [NN*HD];
__device__ __align__(16) u16 g_par[NPAR];
__device__ int   g_src[NE], g_dst[NE], g_batch[NN];
__device__ __align__(16) u16 g_hb[NN*HD];   // residual stream h, bf16
__device__ __align__(16) u16 g_hw[NN*HD];
__device__ __align__(16) u16 g_c[NN*HD];    // conv output, bf16
__device__ float g_asrc[NN*8];
__device__ float g_adst[NN*8];
__device__ int   g_rowptr[NN+1];
__device__ int   g_cursor[NN];
__device__ int   g_bsum[NB], g_boff[NB];
__device__ int   g_csr[NET];
__device__ float g_bnp1[NBN*HD], g_bnp2[NBN*HD];
__device__ float g_scl[HD], g_shf[HD];
__device__ int   g_gcnt[NG], g_goff[NG];
__device__ __align__(16) float g_poolp[NG*NCH*HD];
__device__ __align__(16) u16 g_WT[4][HD*HD];

__device__ __forceinline__ float b2f(u16 u) {
    unsigned v = ((unsigned)u) << 16; float f; __builtin_memcpy(&f, &v, 4); return f;
}
__device__ __forceinline__ u16 f2b(float f) {
    unsigned v; __builtin_memcpy(&v, &f, 4);
    return (u16)((v + 0x7fffu + ((v >> 16) & 1u)) >> 16);   // RNE
}

// wave-uniform dtype probes (64 fixed samples, ballot — deterministic)
__device__ __forceinline__ int probe_f32(const void* xp) {
    const u16* p = (const u16*)xp;
    int ex = (p[threadIdx.x & 63] >> 7) & 0xff;
    return __ballot(ex >= 0x93) != 0ULL;   // |v|>=2^20: impossible for bf16 acts
}
__device__ __forceinline__ int probe_i64(const void* eip) {
    const int* q = (const int*)eip;
    return __ballot(q[2*(threadIdx.x & 63) + 1] != 0) == 0ULL; // i64: high words 0
}

// intra-block inclusive scan (256 threads = 4 waves), shuffle-based
__device__ __forceinline__ int block_incl_scan(int v, int* lds4) {
    int t = threadIdx.x, lane = t & 63, w = t >> 6;
    #pragma unroll
    for (int d = 1; d < 64; d <<= 1) {
        int o = __shfl_up(v, d);
        if (lane >= d) v += o;
    }
    if (lane == 63) lds4[w] = v;
    __syncthreads();
    if (w == 0 && lane < 4) {
        int s = lds4[lane];
        #pragma unroll
        for (int d = 1; d < 4; d <<= 1) {
            int o = __shfl_up(s, d);
            if (lane >= d) s += o;
        }
        lds4[lane] = s;
    }
    __syncthreads();
    if (w > 0) v += lds4[w-1];
    return v;
}

// ---- canonicalize x + params (+ cursor init + flag publish) ----
struct P18 { const void* p[18]; int off[18]; int n[18]; };
__global__ void k_convx(const void* xp, P18 a) {    // grid 6250 x 256
    int gi = blockIdx.x*256 + threadIdx.x;
    int f32 = probe_f32(xp);
    if (gi == 0) g_f32flag = f32;
    if (gi < NN) g_cursor[gi] = 1;           // self-loop pre-count
    int i = gi*4;
    if (f32) {
        float4 v = *(const float4*)((const float*)xp + i);
        ushort4 o = { f2b(v.x), f2b(v.y), f2b(v.z), f2b(v.w) };
        *(ushort4*)&g_x[i] = o;
    } else {
        *(ushort4*)&g_x[i] = *(const ushort4*)((const u16*)xp + i);
    }
    if (blockIdx.x < 64) {                   // folded param conversion
        for (int t = 0; t < 18; ++t) {
            const void* s = a.p[t]; int off = a.off[t], n = a.n[t];
            for (int j = blockIdx.x*256 + threadIdx.x; j < n; j += 64*256)
                g_par[off+j] = f32 ? f2b(((const float*)s)[j]) : ((const u16*)s)[j];
        }
    }
}

// ---- edge/batch conversion + degree count + folded weight transposes ----
__global__ void k_convidx(const void* ei, const void* ba) {   // grid 3125+256
    int b = blockIdx.x;
    if (b >= 3125) {                         // transpose blocks (g_par from k_convx)
        int bb = b - 3125;
        int which = bb >> 6;
        int poff = which==0 ? O_WEMB : which==1 ? O_CW : which==2 ? (O_CW+16384) : O_C2W;
        int idx = (bb & 63)*256 + threadIdx.x;
        int n = idx >> 7, k = idx & 127;
        g_WT[which][n*HD + k] = g_par[poff + k*HD + n];
        return;
    }
    int i64 = probe_i64(ei);
    int e = b*256 + threadIdx.x;
    if (e < NE) {
        int s, d;
        if (i64) { s = (int)((const long long*)ei)[e]; d = (int)((const long long*)ei)[NE + e]; }
        else     { s = ((const int*)ei)[e];            d = ((const int*)ei)[NE + e]; }
        g_src[e] = s; g_dst[e] = d;
        atomicAdd(&g_cursor[d], 1);
    }
    if (e < NN)
        g_batch[e] = i64 ? (int)((const long long*)ba)[e] : ((const int*)ba)[e];
}

// ---- hierarchical exclusive scan of degree counts ----
__global__ void k_blocksum() {
    int i = blockIdx.x*256 + threadIdx.x;
    int v = (i < NN) ? g_cursor[i] : 0;
    #pragma unroll
    for (int d = 32; d; d >>= 1) v += __shfl_down(v, d);
    __shared__ int lds[4];
    if ((threadIdx.x & 63) == 0) lds[threadIdx.x >> 6] = v;
    __syncthreads();
    if (threadIdx.x == 0) g_bsum[blockIdx.x] = lds[0]+lds[1]+lds[2]+lds[3];
}
// ---- small ops: block-sum scan (block 0), graph-offset search (block 1) ----
__global__ void k_misc() {
    int b = blockIdx.x, t = threadIdx.x;
    if (b == 0) {
        __shared__ int lds[4];
        int v = (t < NB) ? g_bsum[t] : 0;
        int incl = block_incl_scan(v, lds);
        if (t < NB) g_boff[t] = incl - v;     // exclusive
    } else {
        __shared__ int off[NG+1];
        if (t <= NG) {
            int lo = 0, hi = NN;
            while (lo < hi) { int mid = (lo+hi) >> 1; if (g_batch[mid] < t) lo = mid+1; else hi = mid; }
            off[t] = lo;
        }
        __syncthreads();
        if (t < NG) { g_goff[t] = off[t]; g_gcnt[t] = off[t+1] - off[t]; }
    }
}
__global__ void k_downsweep() {
    __shared__ int lds[4];
    int i = blockIdx.x*256 + threadIdx.x;
    int c = (i < NN) ? g_cursor[i] : 0;
    int incl = block_incl_scan(c, lds);
    int base = g_boff[blockIdx.x];
    if (i < NN) {
        g_rowptr[i+1] = base + incl;
        g_cursor[i]   = base + incl - c;  // exclusive start = scatter cursor
    }
    if (i == 0) g_rowptr[0] = 0;
}

// ---- scatter, XCD-affine dst partitioning; src loaded only post-check ----
__global__ void k_scatter() {   // grid NTILE*8
    int part = blockIdx.x & 7;
    int e = (blockIdx.x >> 3)*256 + threadIdx.x;
    if (e >= NET) return;
    int d = (e < NE) ? g_dst[e] : e - NE;
    if (d / PSZ != part) return;
    int s = (e < NE) ? g_src[e] : d;
    int pos = atomicAdd(&g_cursor[d], 1);
    g_csr[pos] = s;
}

// ---- shared epilogue helper: att-logit shuffle reduction ----
__device__ __forceinline__ void att_epilogue(f32x4* acc, int row0, int nrows,
                                             int asoff, int adoff, int heads,
                                             int m16, int q) {
    #pragma unroll
    for (int reg = 0; reg < 4; ++reg) {
        float v[8], u[8];
        #pragma unroll
        for (int ct = 0; ct < 8; ++ct) {
            float w = acc[ct][reg];
            v[ct] = w * b2f(g_par[asoff + ct*16 + m16]);
            u[ct] = w * b2f(g_par[adoff + ct*16 + m16]);
        }
        #pragma unroll
        for (int d = 1; d < 16; d <<= 1)
            #pragma unroll
            for (int ct = 0; ct < 8; ++ct) {
                v[ct] += __shfl_xor(v[ct], d);
                u[ct] += __shfl_xor(u[ct], d);
            }
        int r = row0 + q*4 + reg;
        if (m16 == 0 && r < nrows) {
            if (heads == 8) {
                #pragma unroll
                for (int h = 0; h < 8; ++h) {
                    g_asrc[r*8 + h] = v[h];
                    g_adst[r*8 + h] = u[h];
                }
            } else {
                float sv = 0.f, su = 0.f;
                #pragma unroll
                for (int ct = 0; ct < 8; ++ct) { sv += v[ct]; su += u[ct]; }
                g_asrc[r] = sv; g_adst[r] = su;
            }
        }
    }
}

// ---- fused embedding GEMM + layer-0 conv GEMM ----
__global__ __launch_bounds__(256) void k_gemm01() {
    __shared__ __align__(16) u16 wt[HD*136];
    __shared__ __align__(16) u16 ldh[64*136];
    int t = threadIdx.x;
    int lane = t & 63, wave = t >> 6;
    int m16 = lane & 15, q = lane >> 4;
    int row0 = blockIdx.x*64 + wave*16;
    // ---- phase 1: h = x @ W_emb + b_emb ----
    #pragma unroll
    for (int i = 0; i < 8; ++i) {
        int e = (t + i*256) * 8;
        int n = e >> 7, k = e & 127;
        *(uint4*)&wt[n*136 + k] = *(const uint4*)&g_WT[0][e];
    }
    __syncthreads();
    int ra = row0 + m16; if (ra > NN-1) ra = NN-1;
    int rbase = ra*HD + q*8;
    short8 af[4];
    #pragma unroll
    for (int kc = 0; kc < 4; ++kc) af[kc] = *(const short8*)&g_x[rbase + kc*32];
    f32x4 acc[8];
    #pragma unroll
    for (int b = 0; b < 8; ++b) acc[b] = (f32x4){0.f,0.f,0.f,0.f};
    #pragma unroll
    for (int kc = 0; kc < 4; ++kc)
        #pragma unroll
        for (int ct = 0; ct < 8; ++ct) {
            short8 bf = *(const short8*)&wt[(ct*16 + m16)*136 + kc*32 + q*8];
            acc[ct] = __builtin_amdgcn_mfma_f32_16x16x32_bf16(af[kc], bf, acc[ct], 0,0,0);
        }
    #pragma unroll
    for (int reg = 0; reg < 4; ++reg) {
        int rl = wave*16 + q*4 + reg;
        #pragma unroll
        for (int ct = 0; ct < 8; ++ct) {
            int c = ct*16 + m16;
            ldh[rl*136 + c] = f2b(acc[ct][reg] + b2f(g_par[O_BEMB + c]));
        }
    }
    __syncthreads();
    {
        int rl = t >> 2, ck = (t & 3)*32;
        int r = blockIdx.x*64 + rl;
        if (r < NN) {
            uint4 d0 = *(uint4*)&ldh[rl*136 + ck];
            uint4 d1 = *(uint4*)&ldh[rl*136 + ck + 8];
            uint4 d2 = *(uint4*)&ldh[rl*136 + ck + 16];
            uint4 d3 = *(uint4*)&ldh[rl*136 + ck + 24];
            u16* dst = g_hb + r*HD + ck;
            *(uint4*)&dst[0]  = d0; *(uint4*)&dst[8]  = d1;
            *(uint4*)&dst[16] = d2; *(uint4*)&dst[24] = d3;
        }
    }
    // ---- phase 2: hw = h @ W0, att logits (heads=8) ----
    #pragma unroll
    for (int i = 0; i < 8; ++i) {
        int e = (t + i*256) * 8;
        int n = e >> 7, k = e & 127;
        *(uint4*)&wt[n*136 + k] = *(const uint4*)&g_WT[1][e];
    }
    __syncthreads();
    int rl2 = wave*16 + m16;
    #pragma unroll
    for (int kc = 0; kc < 4; ++kc) af[kc] = *(const short8*)&ldh[rl2*136 + kc*32 + q*8];
    #pragma unroll
    for (int b = 0; b < 8; ++b) acc[b] = (f32x4){0.f,0.f,0.f,0.f};
    #pragma unroll
    for (int kc = 0; kc < 4; ++kc)
        #pragma unroll
        for (int ct = 0; ct < 8; ++ct) {
            short8 bf = *(const short8*)&wt[(ct*16 + m16)*136 + kc*32 + q*8];
            acc[ct] = __builtin_amdgcn_mfma_f32_16x16x32_bf16(af[kc], bf, acc[ct], 0,0,0);
        }
    #pragma unroll
    for (int reg = 0; reg < 4; ++reg) {
        int r = row0 + q*4 + reg;
        if (r < NN) {
            #pragma unroll
            for (int ct = 0; ct < 8; ++ct)
                g_hw[r*HD + ct*16 + m16] = f2b(acc[ct][reg]);
        }
    }
    att_epilogue(acc, row0, NN, O_CAS, O_CAD, 8, m16, q);
}

// ---- GEMM (64 rows/block) + fused BN prologue + fused att epilogue ----
__global__ __launch_bounds__(256) void k_gemm(int wsel, int nrows,
                                              int asoff, int adoff, int heads) {
    __shared__ __align__(16) u16 wt[HD*136];
    __shared__ float s_scl[HD], s_shf[HD];
    const u16* WTg = g_WT[wsel];
    int t = threadIdx.x;
    #pragma unroll
    for (int i = 0; i < 8; ++i) {
        int e = (t + i*256) * 8;
        int n = e >> 7, k = e & 127;
        *(uint4*)&wt[n*136 + k] = *(const uint4*)&WTg[e];
    }
    if (t < HD) { s_scl[t] = g_scl[t]; s_shf[t] = g_shf[t]; }
    __syncthreads();
    int lane = t & 63, wave = t >> 6;
    int m16 = lane & 15, q = lane >> 4;
    int row0 = blockIdx.x*64 + wave*16;
    int ra = row0 + m16; if (ra > nrows-1) ra = nrows-1;
    int rbase = ra*HD + q*8;
    short8 af[4];
    short8 cv[4], hv[4];
    #pragma unroll
    for (int kc = 0; kc < 4; ++kc) cv[kc] = *(const short8*)&g_c[rbase + kc*32];
    #pragma unroll
    for (int kc = 0; kc < 4; ++kc) hv[kc] = *(const short8*)&g_hb[rbase + kc*32];
    #pragma unroll
    for (int kc = 0; kc < 4; ++kc) {
        #pragma unroll
        for (int k2 = 0; k2 < 8; ++k2) {
            int ch = kc*32 + q*8 + k2;
            float v = fmaxf(b2f((u16)cv[kc][k2])*s_scl[ch] + s_shf[ch], 0.f)
                      + b2f((u16)hv[kc][k2]);
            af[kc][k2] = (short)f2b(v);
        }
        *(short8*)&g_hb[rbase + kc*32] = af[kc];   // unique per element; dup rows identical
    }
    f32x4 acc[8];
    #pragma unroll
    for (int b = 0; b < 8; ++b) acc[b] = (f32x4){0.f,0.f,0.f,0.f};
    #pragma unroll
    for (int kc = 0; kc < 4; ++kc)
        #pragma unroll
        for (int ct = 0; ct < 8; ++ct) {
            short8 bf = *(const short8*)&wt[(ct*16 + m16)*136 + kc*32 + q*8];
            acc[ct] = __builtin_amdgcn_mfma_f32_16x16x32_bf16(af[kc], bf, acc[ct], 0,0,0);
        }
    #pragma unroll
    for (int reg = 0; reg < 4; ++reg) {
        int r = row0 + q*4 + reg;
        if (r < nrows) {
            #pragma unroll
            for (int ct = 0; ct < 8; ++ct)
                g_hw[r*HD + ct*16 + m16] = f2b(acc[ct][reg]);
        }
    }
    att_epilogue(acc, row0, nrows, asoff, adoff, heads, m16, q);
}

// ---- segment softmax + aggregate: one wave per dst node, 8/4/1 edge batching ----
__global__ __launch_bounds__(256) void k_flash(int boff, int heads, int hs) {
    int node = blockIdx.x*4 + (threadIdx.x >> 6);
    int lane = threadIdx.x & 63;
    int c0 = lane*2;
    int head = c0 >> hs;
    float ad = g_adst[node*heads + head];
    int beg = g_rowptr[node], end = g_rowptr[node+1];
    float l = 0.f, o0 = 0.f, o1 = 0.f;
    int j = beg;
    for (; j + 8 <= end; j += 8) {
        int s[8]; float av[8]; unsigned w[8];
        #pragma unroll
        for (int k = 0; k < 8; ++k) s[k] = g_csr[j+k];
        #pragma unroll
        for (int k = 0; k < 8; ++k) av[k] = g_asrc[s[k]*heads + head];
        #pragma unroll
        for (int k = 0; k < 8; ++k) w[k] = *(const unsigned*)&g_hw[s[k]*HD + c0];
        #pragma unroll
        for (int k = 0; k < 8; ++k) {
            float e = av[k] + ad;
            e = fmaxf(e, 0.2f*e);
            float p = __expf(fminf(e, 30.f));
            l  += p;
            o0 += p*b2f((u16)(w[k] & 0xffff));
            o1 += p*b2f((u16)(w[k] >> 16));
        }
    }
    for (; j + 4 <= end; j += 4) {
        int s[4]; float av[4]; unsigned w[4];
        #pragma unroll
        for (int k = 0; k < 4; ++k) s[k] = g_csr[j+k];
        #pragma unroll
        for (int k = 0; k < 4; ++k) av[k] = g_asrc[s[k]*heads + head];
        #pragma unroll
        for (int k = 0; k < 4; ++k) w[k] = *(const unsigned*)&g_hw[s[k]*HD + c0];
        #pragma unroll
        for (int k = 0; k < 4; ++k) {
            float e = av[k] + ad;
            e = fmaxf(e, 0.2f*e);
            float p = __expf(fminf(e, 30.f));
            l  += p;
            o0 += p*b2f((u16)(w[k] & 0xffff));
            o1 += p*b2f((u16)(w[k] >> 16));
        }
    }
    for (; j < end; ++j) {
        int s = g_csr[j];
        float e = g_asrc[s*heads + head] + ad;
        e = fmaxf(e, 0.2f*e);
        float p = __expf(fminf(e, 30.f));
        unsigned w = *(const unsigned*)&g_hw[s*HD + c0];
        l  += p;
        o0 += p*b2f((u16)(w & 0xffff));
        o1 += p*b2f((u16)(w >> 16));
    }
    float inv = 1.f/l;                       // l>0: self-loop guarantees >=1 edge
    ushort2 o = { f2b(o0*inv + b2f(g_par[boff + c0])),
                  f2b(o1*inv + b2f(g_par[boff + c0 + 1])) };
    *(ushort2*)&g_c[node*HD + c0] = o;       // bf16 store
}

// ---- BatchNorm: per-block partials + parallel reduce (kernel boundary is the
// ---- cheap cross-XCD fence; R11's fence-fused version lost 100us) ----
__global__ void k_bnstats() {
    int t = threadIdx.x; int ch = t & 127, r0 = t >> 7;
    int base = blockIdx.x*128;
    float s = 0.f, q = 0.f;
    for (int i = r0; i < 128; i += 2) {
        int n = base + i;
        if (n < NN) { float v = b2f(g_c[n*HD + ch]); s += v; q += v*v; }
    }
    __shared__ float sS[256], sQ[256];
    sS[t] = s; sQ[t] = q; __syncthreads();
    if (t < 128) {
        g_bnp1[blockIdx.x*HD + t] = sS[t] + sS[t+128];
        g_bnp2[blockIdx.x*HD + t] = sQ[t] + sQ[t+128];
    }
}
__global__ void k_bnfinal(int goff, int boff) {   // 128 blocks x 64
    int ch = blockIdx.x, t = threadIdx.x;
    float s = 0.f, q = 0.f;
    for (int b = t; b < NBN; b += 64) { s += g_bnp1[b*HD + ch]; q += g_bnp2[b*HD + ch]; }
    #pragma unroll
    for (int d = 32; d; d >>= 1) { s += __shfl_down(s, d); q += __shfl_down(q, d); }
    if (t == 0) {
        float mean = s / (float)NN;
        float var  = fmaxf(q / (float)NN - mean*mean, 0.f);
        float sc = b2f(g_par[goff + ch]) * rsqrtf(var + 1e-5f);
        g_scl[ch] = sc;
        g_shf[ch] = b2f(g_par[boff + ch]) - mean*sc;
    }
}

// ---- mean pool, stage 1 + fused layer-2 BN/ReLU/residual (bf16 streams) ----
__global__ void k_pool() {
    int g = blockIdx.x / NCH, c = blockIdx.x - g*NCH;
    int cnt = g_gcnt[g], off = g_goff[g];
    int step = (cnt + NCH - 1) / NCH;
    int r0 = c*step, r1 = min(cnt, r0 + step);
    int t = threadIdx.x;
    int ch = (t & 31) * 4;
    int rr = t >> 5;
    float sc0 = g_scl[ch], sc1 = g_scl[ch+1], sc2 = g_scl[ch+2], sc3 = g_scl[ch+3];
    float sf0 = g_shf[ch], sf1 = g_shf[ch+1], sf2 = g_shf[ch+2], sf3 = g_shf[ch+3];
    float4 s = {0.f,0.f,0.f,0.f};
    for (int i = r0 + rr; i < r1; i += 8) {
        int base = (off + i)*HD + ch;
        ushort4 cv = *(const ushort4*)&g_c[base];
        ushort4 hv = *(const ushort4*)&g_hb[base];
        s.x += fmaxf(b2f(cv.x)*sc0 + sf0, 0.f) + b2f(hv.x);
        s.y += fmaxf(b2f(cv.y)*sc1 + sf1, 0.f) + b2f(hv.y);
        s.z += fmaxf(b2f(cv.z)*sc2 + sf2, 0.f) + b2f(hv.z);
        s.w += fmaxf(b2f(cv.w)*sc3 + sf3, 0.f) + b2f(hv.w);
    }
    __shared__ float4 sh[256];
    sh[t] = s; __syncthreads();
    if (t < 32) {
        float4 a = sh[t];
        #pragma unroll
        for (int k = 1; k < 8; ++k) {
            float4 b = sh[t + k*32];
            a.x += b.x; a.y += b.y; a.z += b.z; a.w += b.w;
        }
        *(float4*)&g_poolp[(g*NCH + c)*HD + ch] = a;
    }
}

// ---- fused head: pool-reduce + lin1 + lin2 + lin3, one block per graph ----
__global__ void k_head(void* outB) {
    __shared__ float pl[HD], h1[HD], h2[HD];
    int g = blockIdx.x, t = threadIdx.x;   // 128 threads
    float s = 0.f;
    for (int c = 0; c < NCH; ++c) s += g_poolp[(g*NCH + c)*HD + t];
    pl[t] = s / fmaxf((float)g_gcnt[g], 1.f);
    __syncthreads();
    float acc = b2f(g_par[O_L1B + t]);
    for (int k = 0; k < HD; ++k) acc += pl[k] * b2f(g_par[O_L1W + k*HD + t]);
    h1[t] = fmaxf(acc, 0.f);
    __syncthreads();
    acc = b2f(g_par[O_L2B + t]);
    for (int k = 0; k < HD; ++k) acc += h1[k] * b2f(g_par[O_L2W + k*HD + t]);
    h2[t] = fmaxf(acc, 0.f);
    __syncthreads();
    if (t < 10) {
        acc = b2f(g_par[O_L3B + t]);
        for (int k = 0; k < HD; ++k) acc += h2[k] * b2f(g_par[O_L3W + k*10 + t]);
        if (g_f32flag) ((float*)outB)[g*10 + t] = acc;
        else           ((u16*)outB)[g*10 + t] = f2b(acc);
    }
}

extern "C" void kernel_launch(void* const* d_in, const int* in_sizes, int n_in,
                              void* d_out, int out_size, void* d_ws, size_t ws_size,
                              hipStream_t stream) {
    const void* x     = d_in[0];
    const void* ei    = d_in[1];
    const void* batch = d_in[3];

    P18 a;
    const int srcidx[18] = {4,5,6,7,8,9,10,11,12,13,14,15,16,17,18,19,20,21};
    const int offs[18] = {O_WEMB,O_BEMB,O_CW,O_CAS,O_CAD,O_CB,O_C2W,O_C2AS,O_C2AD,
                          O_C2B,O_BNG,O_BNB,O_L1W,O_L1B,O_L2W,O_L2B,O_L3W,O_L3B};
    const int lens[18] = {16384,128,32768,256,256,256,16384,128,128,128,384,384,
                          16384,128,16384,128,1280,10};
    for (int t = 0; t < 18; ++t) { a.p[t] = d_in[srcidx[t]]; a.off[t] = offs[t]; a.n[t] = lens[t]; }

    k_convx<<<6250, 256, 0, stream>>>(x, a);          // x + params + cursor + flag
    k_convidx<<<3125 + 256, 256, 0, stream>>>(ei, batch); // edges + batch + transposes
    k_blocksum<<<NB, 256, 0, stream>>>();
    k_misc<<<2, 256, 0, stream>>>();                  // scanb + gidx
    k_downsweep<<<NB, 256, 0, stream>>>();
    k_scatter<<<NTILE*8, 256, 0, stream>>>();         // XCD-affine partitions

    // fused: h = x@W_emb + b  AND  hw = h@W0 + att logits (layer 0)
    k_gemm01<<<NGB, 256, 0, stream>>>();
    k_flash<<<12500, 256, 0, stream>>>(O_CB, 8, 4);
    k_bnstats<<<NBN, 256, 0, stream>>>();
    k_bnfinal<<<128, 64, 0, stream>>>(O_BNG, O_BNB);

    for (int L = 1; L < 3; ++L) {
        int heads = (L < 2) ? 8 : 1;
        int hs    = (L < 2) ? 4 : 7;
        int as    = (L < 2) ? O_CAS + L*128 : O_C2AS;
        int ad    = (L < 2) ? O_CAD + L*128 : O_C2AD;
        int cb    = (L < 2) ? O_CB  + L*128 : O_C2B;
        k_gemm<<<NGB, 256, 0, stream>>>(L+1, NN, as, ad, heads);  // BN(L-1) fused prologue
        k_flash<<<12500, 256, 0, stream>>>(cb, heads, hs);
        k_bnstats<<<NBN, 256, 0, stream>>>();
        k_bnfinal<<<128, 64, 0, stream>>>(O_BNG + L*HD, O_BNB + L*HD);
    }

    k_pool<<<NG*NCH, 256, 0, stream>>>();             // + fused layer-2 BN/residual
    k_head<<<NG, 128, 0, stream>>>(d_out);
}